// Round 1
// baseline (364.282 us; speedup 1.0000x reference)
//
#include <hip/hip_runtime.h>
#include <hip/hip_bf16.h>
#include <math.h>

// Problem constants
#define BB   256   // batch
#define INW  512   // IN
#define HH   1024  // H
#define OUTW 512   // OUT
#define SS   512   // S (memory slots)
#define WD   256   // Wd (word size)
#define P_READ  262  // Wd + 2 + SH + 1
#define P_WRITE 774  // P_READ + 2*Wd

// ---------------- small device helpers ----------------
__device__ __forceinline__ float sigmoidf(float x) { return 1.f / (1.f + expf(-x)); }
__device__ __forceinline__ float softplusf(float x) { return (x > 20.f) ? x : log1pf(expf(x)); }

__device__ __forceinline__ float blockReduceSum256(float v, volatile float* red) {
    #pragma unroll
    for (int off = 32; off > 0; off >>= 1) v += __shfl_down(v, off, 64);
    int wid = threadIdx.x >> 6;
    __syncthreads();
    if ((threadIdx.x & 63) == 0) red[wid] = v;
    __syncthreads();
    return red[0] + red[1] + red[2] + red[3];
}

__device__ __forceinline__ float blockReduceMax256(float v, volatile float* red) {
    #pragma unroll
    for (int off = 32; off > 0; off >>= 1) v = fmaxf(v, __shfl_down(v, off, 64));
    int wid = threadIdx.x >> 6;
    __syncthreads();
    if ((threadIdx.x & 63) == 0) red[wid] = v;
    __syncthreads();
    return fmaxf(fmaxf(red[0], red[1]), fmaxf(red[2], red[3]));
}

// ---------------- generic f32 GEMM: C[m,n] = sum_k A[m,k]*B[n,k] (+bias1[n]+bias2[n]) ----------------
// M multiple of 64 (grid.y = M/64). N may be ragged. K multiple of 32.
// LDS tiles stored transposed [k][m] so inner reads are float4 and <=2-way bank conflicts.
#define GT_M 64
#define GT_N 64
#define GT_K 32
#define LDT  68   // padded tile row stride (floats), keeps float4 alignment + bank spread

__global__ __launch_bounds__(256)
void gemm_abt(const float* __restrict__ A, int lda,
              const float* __restrict__ B, int ldb,
              const float* __restrict__ bias1, const float* __restrict__ bias2,
              float* __restrict__ C, int ldc, int N, int K)
{
    __shared__ __align__(16) float As[GT_K][LDT];
    __shared__ __align__(16) float Bs[GT_K][LDT];
    const int tid = threadIdx.x;
    const int bm = blockIdx.y * GT_M;
    const int bn = blockIdx.x * GT_N;
    const int tx = tid & 15, ty = tid >> 4;
    const int lr = tid >> 3;           // 0..31
    const int lc = (tid & 7) << 2;     // 0,4,...,28

    float acc[4][4] = {{0.f}};

    for (int k0 = 0; k0 < K; k0 += GT_K) {
        #pragma unroll
        for (int half = 0; half < 2; ++half) {
            int r = lr + half * 32;
            float4 av = *reinterpret_cast<const float4*>(A + (size_t)(bm + r) * lda + k0 + lc);
            int nrow = bn + r;
            float4 bv = make_float4(0.f, 0.f, 0.f, 0.f);
            if (nrow < N)
                bv = *reinterpret_cast<const float4*>(B + (size_t)nrow * ldb + k0 + lc);
            As[lc + 0][r] = av.x; As[lc + 1][r] = av.y; As[lc + 2][r] = av.z; As[lc + 3][r] = av.w;
            Bs[lc + 0][r] = bv.x; Bs[lc + 1][r] = bv.y; Bs[lc + 2][r] = bv.z; Bs[lc + 3][r] = bv.w;
        }
        __syncthreads();
        #pragma unroll
        for (int k = 0; k < GT_K; ++k) {
            float4 a = *reinterpret_cast<const float4*>(&As[k][ty << 2]);
            float4 b = *reinterpret_cast<const float4*>(&Bs[k][tx << 2]);
            acc[0][0] += a.x * b.x; acc[0][1] += a.x * b.y; acc[0][2] += a.x * b.z; acc[0][3] += a.x * b.w;
            acc[1][0] += a.y * b.x; acc[1][1] += a.y * b.y; acc[1][2] += a.y * b.z; acc[1][3] += a.y * b.w;
            acc[2][0] += a.z * b.x; acc[2][1] += a.z * b.y; acc[2][2] += a.z * b.z; acc[2][3] += a.z * b.w;
            acc[3][0] += a.w * b.x; acc[3][1] += a.w * b.y; acc[3][2] += a.w * b.z; acc[3][3] += a.w * b.w;
        }
        __syncthreads();
    }

    #pragma unroll
    for (int i = 0; i < 4; ++i) {
        int m = bm + (ty << 2) + i;
        #pragma unroll
        for (int j = 0; j < 4; ++j) {
            int n = bn + (tx << 2) + j;
            if (n < N) {
                float v = acc[i][j];
                if (bias1) v += bias1[n];
                if (bias2) v += bias2[n];
                C[(size_t)m * ldc + n] = v;
            }
        }
    }
}

// ---------------- prep: memory transpose + row norms (memory == broadcast mem_bias) ----------------
__global__ __launch_bounds__(256)
void prep_kernel(const float* __restrict__ mem, float* __restrict__ memT,
                 float* __restrict__ mem_norm)
{
    __shared__ float red[4];
    int s = blockIdx.x;       // 0..511
    int t = threadIdx.x;      // 0..255  (= w)
    float v = mem[(size_t)s * WD + t];
    memT[(size_t)t * SS + s] = v;
    float sum = blockReduceSum256(v * v, red);
    if (t == 0) mem_norm[s] = fmaxf(sqrtf(sum), 1e-8f);
}

// ---------------- LSTM activation from compact gates (i | g | o), biases already folded in GEMM ----------------
__global__ __launch_bounds__(256)
void lstm_act_kernel(const float* __restrict__ gc, float* __restrict__ h)
{
    int idx = blockIdx.x * 256 + threadIdx.x;   // 0 .. 256*1024-1
    int b = idx >> 10;
    int j = idx & 1023;
    const float* g = gc + (size_t)b * 3072;
    float gi = g[j];
    float gg = g[1024 + j];
    float go = g[2048 + j];
    float c = sigmoidf(gi) * tanhf(gg);
    h[idx] = sigmoidf(go) * tanhf(c);
}

// ---------------- NTM addressing (content + gate + shift + sharpen) ----------------
// grid: (256 batches, 2 which) ; block 256. which==0 -> read (rp,P_READ), which==1 -> write (wp,P_WRITE)
__global__ __launch_bounds__(256)
void address_kernel(const float* __restrict__ rp, const float* __restrict__ wp,
                    const float* __restrict__ mem, const float* __restrict__ mem_norm,
                    float* __restrict__ read_w, float* __restrict__ write_w)
{
    int b = blockIdx.x;
    int which = blockIdx.y;
    const float* p = which ? (wp + (size_t)b * P_WRITE) : (rp + (size_t)b * P_READ);
    float* outw = (which ? write_w : read_w) + (size_t)b * SS;
    int t = threadIdx.x;

    __shared__ __align__(16) float key[WD];
    __shared__ float buf[SS];
    __shared__ float red[4];

    float kv_own = p[t];
    key[t] = kv_own;
    __syncthreads();

    // header params (redundant per-thread, 6 broadcast global reads)
    float beta  = softplusf(p[WD]);
    float gate  = sigmoidf(p[WD + 1]);
    float s0r = p[WD + 2], s1r = p[WD + 3], s2r = p[WD + 4];
    float smx = fmaxf(s0r, fmaxf(s1r, s2r));
    float e0 = expf(s0r - smx), e1 = expf(s1r - smx), e2 = expf(s2r - smx);
    float einv = 1.f / (e0 + e1 + e2);
    float sh0 = e0 * einv, sh1 = e1 * einv, sh2 = e2 * einv;
    float gamma = 1.f + softplusf(p[WD + 5]);

    // key norm
    float ksum = blockReduceSum256(kv_own * kv_own, red);
    float kn = fmaxf(sqrtf(ksum), 1e-8f);

    // cosine sims for s = t and s = t+256
    float num0 = 0.f, num1 = 0.f;
    const float4* m0 = reinterpret_cast<const float4*>(mem + (size_t)t * WD);
    const float4* m1 = reinterpret_cast<const float4*>(mem + (size_t)(t + 256) * WD);
    #pragma unroll 8
    for (int w4 = 0; w4 < WD / 4; ++w4) {
        float4 kv = *reinterpret_cast<const float4*>(&key[w4 * 4]);
        float4 a0 = m0[w4];
        float4 a1 = m1[w4];
        num0 += kv.x * a0.x + kv.y * a0.y + kv.z * a0.z + kv.w * a0.w;
        num1 += kv.x * a1.x + kv.y * a1.y + kv.z * a1.z + kv.w * a1.w;
    }
    float sim0 = num0 / (kn * mem_norm[t]) * beta;
    float sim1 = num1 / (kn * mem_norm[t + 256]) * beta;

    // softmax over 512 slots
    float mx = blockReduceMax256(fmaxf(sim0, sim1), red);
    float ex0 = expf(sim0 - mx), ex1 = expf(sim1 - mx);
    float ssum = blockReduceSum256(ex0 + ex1, red);
    float sinv = 1.f / ssum;
    float cw0 = ex0 * sinv, cw1 = ex1 * sinv;

    // gate with prev_w = one-hot(0)
    float gw0 = gate * cw0 + (1.f - gate) * (t == 0 ? 1.f : 0.f);
    float gw1 = gate * cw1;
    buf[t] = gw0;
    buf[t + 256] = gw1;
    __syncthreads();

    // cyclic shift conv
    float sw0 = sh0 * buf[(t + SS - 1) & (SS - 1)] + sh1 * gw0 + sh2 * buf[(t + 1) & (SS - 1)];
    int s1i = t + 256;
    float sw1 = sh0 * buf[(s1i + SS - 1) & (SS - 1)] + sh1 * gw1 + sh2 * buf[(s1i + 1) & (SS - 1)];

    // sharpen + normalize
    float sp0 = powf(sw0, gamma), sp1 = powf(sw1, gamma);
    float spsum = blockReduceSum256(sp0 + sp1, red) + 1e-6f;
    float dinv = 1.f / spsum;
    outw[t] = sp0 * dinv;
    outw[t + 256] = sp1 * dinv;
}

// ---------------- rw product + t3 ----------------
__global__ __launch_bounds__(256)
void rw_prep_kernel(const float* __restrict__ read_w, const float* __restrict__ write_w,
                    float* __restrict__ rw_prod, float* __restrict__ t3)
{
    __shared__ float red[4];
    int b = blockIdx.x, t = threadIdx.x;
    float r0 = read_w[(size_t)b * SS + t],        r1 = read_w[(size_t)b * SS + t + 256];
    float w0 = write_w[(size_t)b * SS + t],       w1 = write_w[(size_t)b * SS + t + 256];
    float p0 = r0 * w0, p1 = r1 * w1;
    rw_prod[(size_t)b * SS + t] = p0;
    rw_prod[(size_t)b * SS + t + 256] = p1;
    float s = blockReduceSum256(p0 + p1, red);
    if (t == 0) t3[b] = s;
}

// ---------------- rv from analytic memory-update decomposition ----------------
// rv[b,w] = t1[b,w] - erase[b,w]*t2[b,w] + add[b,w]*t3[b]
__global__ __launch_bounds__(256)
void rv_kernel(const float* __restrict__ t12, const float* __restrict__ wp,
               const float* __restrict__ t3, float* __restrict__ rv)
{
    int b = blockIdx.x, w = threadIdx.x;
    float t1 = t12[(size_t)b * WD + w];
    float t2 = t12[(size_t)(256 + b) * WD + w];
    const float* wpb = wp + (size_t)b * P_WRITE;
    float e = sigmoidf(wpb[P_READ + w]);
    float a = tanhf(wpb[P_READ + WD + w]);
    rv[(size_t)b * WD + w] = t1 - e * t2 + a * t3[b];
}

// ---------------- concat [h | rv] ----------------
__global__ __launch_bounds__(256)
void concat_kernel(const float* __restrict__ h, const float* __restrict__ rv,
                   float* __restrict__ hrv)
{
    int idx = blockIdx.x * 256 + threadIdx.x;  // 0 .. 256*1280-1
    int b = idx / 1280;
    int j = idx - b * 1280;
    float v = (j < HH) ? h[(size_t)b * HH + j] : rv[(size_t)b * WD + (j - HH)];
    hrv[idx] = v;
}

// ---------------- host launcher ----------------
extern "C" void kernel_launch(void* const* d_in, const int* in_sizes, int n_in,
                              void* d_out, int out_size, void* d_ws, size_t ws_size,
                              hipStream_t stream)
{
    const float* x       = (const float*)d_in[0];
    const float* W_ih    = (const float*)d_in[1];
    const float* b_ih    = (const float*)d_in[2];
    // d_in[3] = W_hh : unused (h0 == 0)
    const float* b_hh    = (const float*)d_in[4];
    const float* W_read  = (const float*)d_in[5];
    const float* b_read  = (const float*)d_in[6];
    const float* W_write = (const float*)d_in[7];
    const float* b_write = (const float*)d_in[8];
    const float* W_out   = (const float*)d_in[9];
    const float* b_out   = (const float*)d_in[10];
    const float* mem     = (const float*)d_in[11];

    float* ws = (float*)d_ws;
    float* gates_c  = ws;               // 256*3072 = 786432
    float* h        = ws + 786432;      // 256*1024 = 262144
    float* rp       = ws + 1048576;     // 256*262  = 67072
    float* wp       = ws + 1115648;     // 256*774  = 198144
    float* read_w   = ws + 1313792;     // 256*512  = 131072
    float* rw_prod  = ws + 1444864;     // 256*512  = 131072  (contiguous after read_w!)
    float* write_w  = ws + 1575936;     // 256*512
    float* memT     = ws + 1707008;     // 256*512
    float* t12      = ws + 1838080;     // 512*256
    float* t3       = ws + 1969152;     // 256
    float* mem_norm = ws + 1969408;     // 512
    float* rv       = ws + 1969920;     // 256*256 = 65536
    float* hrv      = ws + 2035456;     // 256*1280 = 327680
    float* out      = (float*)d_out;

    // memory norms + transpose (independent of everything else)
    prep_kernel<<<SS, 256, 0, stream>>>(mem, memT, mem_norm);

    // gates (compact: i | g | o), f-gate skipped since c0==0; rv0==0 so only first 512 cols of W_ih
    gemm_abt<<<dim3(16, 4), 256, 0, stream>>>(x, INW, W_ih, INW + WD,
                                              b_ih, b_hh, gates_c, 3072, 1024, INW);
    gemm_abt<<<dim3(32, 4), 256, 0, stream>>>(x, INW, W_ih + (size_t)2048 * (INW + WD), INW + WD,
                                              b_ih + 2048, b_hh + 2048, gates_c + 1024, 3072, 2048, INW);
    lstm_act_kernel<<<1024, 256, 0, stream>>>(gates_c, h);

    // read / write parameter projections
    gemm_abt<<<dim3(5, 4), 256, 0, stream>>>(h, HH, W_read, HH, b_read, nullptr, rp, P_READ, P_READ, HH);
    gemm_abt<<<dim3(13, 4), 256, 0, stream>>>(h, HH, W_write, HH, b_write, nullptr, wp, P_WRITE, P_WRITE, HH);

    // addressing (read & write in one launch)
    address_kernel<<<dim3(BB, 2), 256, 0, stream>>>(rp, wp, mem, mem_norm, read_w, write_w);

    // rw product + t3
    rw_prep_kernel<<<BB, 256, 0, stream>>>(read_w, write_w, rw_prod, t3);

    // t1 (rows 0..255) and t2 (rows 256..511) in one GEMM: [read_w; rw_prod] @ mem
    gemm_abt<<<dim3(4, 8), 256, 0, stream>>>(read_w, SS, memT, SS, nullptr, nullptr, t12, WD, WD, SS);

    // rv
    rv_kernel<<<BB, 256, 0, stream>>>(t12, wp, t3, rv);

    // out = [h | rv] @ W_out^T + b_out
    concat_kernel<<<1280, 256, 0, stream>>>(h, rv, hrv);
    gemm_abt<<<dim3(8, 4), 256, 0, stream>>>(hrv, HH + WD, W_out, HH + WD, b_out, nullptr, out, OUTW, OUTW, HH + WD);
}

// Round 2
// 83.817 us; speedup vs baseline: 4.3462x; 4.3462x over previous
//
#include <hip/hip_runtime.h>
#include <hip/hip_bf16.h>
#include <math.h>

// Problem constants
#define BB   256
#define INW  512
#define HH   1024
#define OUTW 512
#define SS   512
#define WD   256
#define P_READ  262
#define P_WRITE 774

typedef __attribute__((ext_vector_type(8))) short bf16x8;
typedef __attribute__((ext_vector_type(4))) float f32x4;

__device__ __forceinline__ float sigmoidf(float x) { return 1.f / (1.f + expf(-x)); }
__device__ __forceinline__ float softplusf(float x) { return (x > 20.f) ? x : log1pf(expf(x)); }

__device__ __forceinline__ float blockReduceSum256(float v, volatile float* red) {
    #pragma unroll
    for (int off = 32; off > 0; off >>= 1) v += __shfl_down(v, off, 64);
    int wid = threadIdx.x >> 6;
    __syncthreads();
    if ((threadIdx.x & 63) == 0) red[wid] = v;
    __syncthreads();
    return red[0] + red[1] + red[2] + red[3];
}

__device__ __forceinline__ float blockReduceMax256(float v, volatile float* red) {
    #pragma unroll
    for (int off = 32; off > 0; off >>= 1) v = fmaxf(v, __shfl_down(v, off, 64));
    int wid = threadIdx.x >> 6;
    __syncthreads();
    if ((threadIdx.x & 63) == 0) red[wid] = v;
    __syncthreads();
    return fmaxf(fmaxf(red[0], red[1]), fmaxf(red[2], red[3]));
}

// ---------------- one-shot conversion / packing to bf16 ----------------
#define N_WIH (3072*512)
#define N_WR  (272*1024)
#define N_WW  (784*1024)
#define N_WO  (512*1280)
#define N_X   (256*512)
#define N_MB  (512*256)
#define N_MT  (256*512)
#define N_BIA 3072
#define N_TOT (N_WIH+N_WR+N_WW+N_WO+N_X+N_MB+N_MT+N_BIA)

__global__ __launch_bounds__(256)
void convert_all(const float* __restrict__ W_ih, const float* __restrict__ b_ih,
                 const float* __restrict__ b_hh,
                 const float* __restrict__ W_read, const float* __restrict__ W_write,
                 const float* __restrict__ W_out, const float* __restrict__ x,
                 const float* __restrict__ mem,
                 __hip_bfloat16* __restrict__ Wih_c, __hip_bfloat16* __restrict__ Wr_p,
                 __hip_bfloat16* __restrict__ Ww_p, __hip_bfloat16* __restrict__ Wo_b,
                 __hip_bfloat16* __restrict__ x_b, __hip_bfloat16* __restrict__ mem_b,
                 __hip_bfloat16* __restrict__ memT_b, float* __restrict__ bias_c)
{
    long i = (long)blockIdx.x * 256 + threadIdx.x;
    if (i >= N_TOT) return;
    if (i < N_WIH) {
        int r = (int)(i >> 9), c = (int)(i & 511);
        int sr = r < 1024 ? r : r + 1024;
        Wih_c[i] = __float2bfloat16(W_ih[(size_t)sr * 768 + c]);
        return;
    }
    i -= N_WIH;
    if (i < N_WR) {
        int r = (int)(i >> 10), c = (int)(i & 1023);
        Wr_p[i] = __float2bfloat16(r < P_READ ? W_read[(size_t)r * 1024 + c] : 0.f);
        return;
    }
    i -= N_WR;
    if (i < N_WW) {
        int r = (int)(i >> 10), c = (int)(i & 1023);
        Ww_p[i] = __float2bfloat16(r < P_WRITE ? W_write[(size_t)r * 1024 + c] : 0.f);
        return;
    }
    i -= N_WW;
    if (i < N_WO) { Wo_b[i] = __float2bfloat16(W_out[i]); return; }
    i -= N_WO;
    if (i < N_X)  { x_b[i] = __float2bfloat16(x[i]); return; }
    i -= N_X;
    if (i < N_MB) { mem_b[i] = __float2bfloat16(mem[i]); return; }
    i -= N_MB;
    if (i < N_MT) {
        int w = (int)(i >> 9), s = (int)(i & 511);
        memT_b[i] = __float2bfloat16(mem[(size_t)s * 256 + w]);
        return;
    }
    i -= N_MT;
    { // bias_c
        int r = (int)i;
        int sr = r < 1024 ? r : r + 1024;
        bias_c[r] = b_ih[sr] + b_hh[sr];
    }
}

// ---------------- memory row norms ----------------
__global__ __launch_bounds__(256)
void prep_norms(const float* __restrict__ mem, float* __restrict__ mem_norm)
{
    __shared__ float red[4];
    int s = blockIdx.x;
    float v = mem[(size_t)s * WD + threadIdx.x];
    float sum = blockReduceSum256(v * v, red);
    if (threadIdx.x == 0) mem_norm[s] = fmaxf(sqrtf(sum), 1e-8f);
}

// ---------------- MFMA GEMM: C[m,n] = sum_k A[m,k]*B[n,k] (+bias[n]) ----------------
// One wave (64 threads) per 16x16 output tile. No LDS, no barriers; data is L2-resident.
// A [M x lda] bf16, B [N_pad x ldb] bf16 (rows padded w/ zeros to mult of 16), K mult of 32.
// Optional: copy C cols [0,256) as bf16 into kcopy at row offset krow0 (keys harvest).
__global__ __launch_bounds__(64)
void gemm_mfma(const __hip_bfloat16* __restrict__ A, int lda,
               const __hip_bfloat16* __restrict__ B, int ldb,
               const float* __restrict__ bias,
               float* __restrict__ C, int ldc, int N, int K,
               __hip_bfloat16* __restrict__ kcopy, int krow0)
{
    const int l = threadIdx.x;
    const int bn = blockIdx.x * 16;
    const int bm = blockIdx.y * 16;
    const int r = l & 15, q = l >> 4;
    const __hip_bfloat16* aptr = A + (size_t)(bm + r) * lda + q * 8;
    const __hip_bfloat16* bptr = B + (size_t)(bn + r) * ldb + q * 8;
    f32x4 acc = {0.f, 0.f, 0.f, 0.f};
    #pragma unroll 4
    for (int k = 0; k < K; k += 32) {
        bf16x8 a = *reinterpret_cast<const bf16x8*>(aptr + k);
        bf16x8 b = *reinterpret_cast<const bf16x8*>(bptr + k);
        acc = __builtin_amdgcn_mfma_f32_16x16x32_bf16(a, b, acc, 0, 0, 0);
    }
    const int col = bn + r;
    if (col < N) {
        float bv = bias ? bias[col] : 0.f;
        #pragma unroll
        for (int j = 0; j < 4; ++j) {
            int m = bm + q * 4 + j;
            float v = acc[j] + bv;
            C[(size_t)m * ldc + col] = v;
            if (kcopy && col < WD)
                kcopy[(size_t)(krow0 + m) * WD + col] = __float2bfloat16(v);
        }
    }
}

// ---------------- LSTM activation: compact gates (i|g|o) -> h (bf16, into hrv cols 0..1023) ----------------
__global__ __launch_bounds__(256)
void lstm_act(const float* __restrict__ gc, __hip_bfloat16* __restrict__ hrv)
{
    int idx = blockIdx.x * 256 + threadIdx.x;   // 256*1024
    int b = idx >> 10, j = idx & 1023;
    const float* g = gc + (size_t)b * 3072;
    float c = sigmoidf(g[j]) * tanhf(g[1024 + j]);
    hrv[(size_t)b * 1280 + j] = __float2bfloat16(sigmoidf(g[2048 + j]) * tanhf(c));
}

// ---------------- NTM addressing from precomputed num = keys @ mem^T ----------------
// grid (256 batches, 2 which); block 256
__global__ __launch_bounds__(256)
void address_kernel(const float* __restrict__ rp, const float* __restrict__ wp,
                    const float* __restrict__ num, const float* __restrict__ mem_norm,
                    float* __restrict__ read_w, float* __restrict__ write_w)
{
    int b = blockIdx.x;
    int which = blockIdx.y;
    const float* p = which ? (wp + (size_t)b * P_WRITE) : (rp + (size_t)b * P_READ);
    const float* nrow = num + (size_t)(which * 256 + b) * SS;
    float* outw = (which ? write_w : read_w) + (size_t)b * SS;
    int t = threadIdx.x;

    __shared__ float buf[SS];
    __shared__ float red[4];

    float kv = p[t];                       // key element (t<256 == WD)
    float beta  = softplusf(p[WD]);
    float gate  = sigmoidf(p[WD + 1]);
    float s0r = p[WD + 2], s1r = p[WD + 3], s2r = p[WD + 4];
    float smx = fmaxf(s0r, fmaxf(s1r, s2r));
    float e0 = expf(s0r - smx), e1 = expf(s1r - smx), e2 = expf(s2r - smx);
    float einv = 1.f / (e0 + e1 + e2);
    float sh0 = e0 * einv, sh1 = e1 * einv, sh2 = e2 * einv;
    float gamma = 1.f + softplusf(p[WD + 5]);

    float ksum = blockReduceSum256(kv * kv, red);
    float kn = fmaxf(sqrtf(ksum), 1e-8f);

    float sim0 = nrow[t]       / (kn * mem_norm[t])       * beta;
    float sim1 = nrow[t + 256] / (kn * mem_norm[t + 256]) * beta;

    float mx = blockReduceMax256(fmaxf(sim0, sim1), red);
    float ex0 = expf(sim0 - mx), ex1 = expf(sim1 - mx);
    float ssum = blockReduceSum256(ex0 + ex1, red);
    float sinv = 1.f / ssum;
    float cw0 = ex0 * sinv, cw1 = ex1 * sinv;

    float gw0 = gate * cw0 + (1.f - gate) * (t == 0 ? 1.f : 0.f);
    float gw1 = gate * cw1;
    buf[t] = gw0;
    buf[t + 256] = gw1;
    __syncthreads();

    float sw0 = sh0 * buf[(t + SS - 1) & (SS - 1)] + sh1 * gw0 + sh2 * buf[(t + 1) & (SS - 1)];
    int s1i = t + 256;
    float sw1 = sh0 * buf[(s1i + SS - 1) & (SS - 1)] + sh1 * gw1 + sh2 * buf[(s1i + 1) & (SS - 1)];

    float sp0 = powf(sw0, gamma), sp1 = powf(sw1, gamma);
    float spsum = blockReduceSum256(sp0 + sp1, red) + 1e-6f;
    float dinv = 1.f / spsum;
    outw[t] = sp0 * dinv;
    outw[t + 256] = sp1 * dinv;
}

// ---------------- pack [read_w ; read_w*write_w] as bf16 A12, and t3 ----------------
__global__ __launch_bounds__(256)
void rw_kernel(const float* __restrict__ read_w, const float* __restrict__ write_w,
               __hip_bfloat16* __restrict__ A12, float* __restrict__ t3)
{
    __shared__ float red[4];
    int b = blockIdx.x, t = threadIdx.x;
    float r0 = read_w[(size_t)b * SS + t],  r1 = read_w[(size_t)b * SS + t + 256];
    float w0 = write_w[(size_t)b * SS + t], w1 = write_w[(size_t)b * SS + t + 256];
    float p0 = r0 * w0, p1 = r1 * w1;
    A12[(size_t)b * SS + t] = __float2bfloat16(r0);
    A12[(size_t)b * SS + t + 256] = __float2bfloat16(r1);
    A12[(size_t)(256 + b) * SS + t] = __float2bfloat16(p0);
    A12[(size_t)(256 + b) * SS + t + 256] = __float2bfloat16(p1);
    float s = blockReduceSum256(p0 + p1, red);
    if (t == 0) t3[b] = s;
}

// ---------------- rv = t1 - erase*t2 + add*t3 -> hrv cols 1024..1279 (bf16) ----------------
__global__ __launch_bounds__(256)
void rv_kernel(const float* __restrict__ t12, const float* __restrict__ wp,
               const float* __restrict__ t3, __hip_bfloat16* __restrict__ hrv)
{
    int b = blockIdx.x, w = threadIdx.x;
    float t1 = t12[(size_t)b * WD + w];
    float t2 = t12[(size_t)(256 + b) * WD + w];
    const float* wpb = wp + (size_t)b * P_WRITE;
    float e = sigmoidf(wpb[P_READ + w]);
    float a = tanhf(wpb[P_READ + WD + w]);
    hrv[(size_t)b * 1280 + 1024 + w] = __float2bfloat16(t1 - e * t2 + a * t3[b]);
}

// ---------------- host launcher ----------------
extern "C" void kernel_launch(void* const* d_in, const int* in_sizes, int n_in,
                              void* d_out, int out_size, void* d_ws, size_t ws_size,
                              hipStream_t stream)
{
    const float* x       = (const float*)d_in[0];
    const float* W_ih    = (const float*)d_in[1];
    const float* b_ih    = (const float*)d_in[2];
    const float* b_hh    = (const float*)d_in[4];
    const float* W_read  = (const float*)d_in[5];
    const float* b_read  = (const float*)d_in[6];
    const float* W_write = (const float*)d_in[7];
    const float* b_write = (const float*)d_in[8];
    const float* W_out   = (const float*)d_in[9];
    const float* b_out   = (const float*)d_in[10];
    const float* mem     = (const float*)d_in[11];

    float* ws = (float*)d_ws;
    // f32 region (aliased: gates region reused after lstm_act consumes it)
    float* gates    = ws;                       // 256*3072 = 786432 f
    float* num      = ws;                       // 512*512  = 262144 f   (after lstm)
    float* read_w   = ws + 262144;              // 256*512
    float* write_w  = ws + 393216;              // 256*512
    float* t12      = ws + 524288;              // 512*256
    __hip_bfloat16* A12 = (__hip_bfloat16*)(ws + 655360);  // 512*512 bf16 = 131072 f
    float* rp       = ws + 786432;              // 256*262 = 67072
    float* wp       = ws + 853504;              // 256*774 = 198144
    float* bias_c   = ws + 1051648;             // 3072
    float* mem_norm = ws + 1054720;             // 512
    float* t3       = ws + 1055232;             // 256
    __hip_bfloat16* bfb = (__hip_bfloat16*)(ws + 1055488);
    __hip_bfloat16* x_b    = bfb;               // 131072
    __hip_bfloat16* Wih_c  = bfb + 131072;      // 1572864
    __hip_bfloat16* Wr_p   = bfb + 1703936;     // 278528
    __hip_bfloat16* Ww_p   = bfb + 1982464;     // 802816
    __hip_bfloat16* Wo_b   = bfb + 2785280;     // 655360
    __hip_bfloat16* mem_b  = bfb + 3440640;     // 131072
    __hip_bfloat16* memT_b = bfb + 3571712;     // 131072
    __hip_bfloat16* hrv    = bfb + 3702784;     // 327680
    __hip_bfloat16* keys   = bfb + 4030464;     // 131072
    float* out = (float*)d_out;

    // 1. convert/pack everything to bf16 (+ compact bias)
    convert_all<<<(N_TOT + 255) / 256, 256, 0, stream>>>(
        W_ih, b_ih, b_hh, W_read, W_write, W_out, x, mem,
        Wih_c, Wr_p, Ww_p, Wo_b, x_b, mem_b, memT_b, bias_c);
    // 2. memory row norms
    prep_norms<<<SS, 256, 0, stream>>>(mem, mem_norm);
    // 3. gates = x @ Wih_c^T + bias_c   [256 x 3072]
    gemm_mfma<<<dim3(192, 16), 64, 0, stream>>>(x_b, INW, Wih_c, INW, bias_c,
                                                gates, 3072, 3072, INW, nullptr, 0);
    // 4. h (bf16) into hrv[:, 0:1024]
    lstm_act<<<1024, 256, 0, stream>>>(gates, hrv);
    // 5. rp = h @ W_read^T + b_read ; harvest read keys (rows 0..255)
    gemm_mfma<<<dim3(17, 16), 64, 0, stream>>>(hrv, 1280, Wr_p, HH, b_read,
                                               rp, P_READ, P_READ, HH, keys, 0);
    // 6. wp = h @ W_write^T + b_write ; harvest write keys (rows 256..511)
    gemm_mfma<<<dim3(49, 16), 64, 0, stream>>>(hrv, 1280, Ww_p, HH, b_write,
                                               wp, P_WRITE, P_WRITE, HH, keys, 256);
    // 7. num = keys @ mem^T   [512 x 512]
    gemm_mfma<<<dim3(32, 32), 64, 0, stream>>>(keys, WD, mem_b, WD, nullptr,
                                               num, SS, SS, WD, nullptr, 0);
    // 8. addressing (read & write)
    address_kernel<<<dim3(BB, 2), 256, 0, stream>>>(rp, wp, num, mem_norm, read_w, write_w);
    // 9. A12 = [read_w ; read_w*write_w] bf16, t3
    rw_kernel<<<BB, 256, 0, stream>>>(read_w, write_w, A12, t3);
    // 10. t12 = A12 @ memT^T  -> [512 x 256] (t1 rows 0..255, t2 rows 256..511)
    gemm_mfma<<<dim3(16, 32), 64, 0, stream>>>(A12, SS, memT_b, SS, nullptr,
                                               t12, WD, WD, SS, nullptr, 0);
    // 11. rv -> hrv[:, 1024:1280]
    rv_kernel<<<BB, 256, 0, stream>>>(t12, wp, t3, hrv);
    // 12. out = hrv @ W_out^T + b_out
    gemm_mfma<<<dim3(32, 16), 64, 0, stream>>>(hrv, 1280, Wo_b, 1280, b_out,
                                               out, OUTW, OUTW, 1280, nullptr, 0);
}

// Round 3
// 67.963 us; speedup vs baseline: 5.3600x; 1.2333x over previous
//
#include <hip/hip_runtime.h>
#include <hip/hip_bf16.h>
#include <math.h>

// Problem constants
#define BB   256
#define INW  512
#define HH   1024
#define OUTW 512
#define SS   512
#define WD   256
#define P_READ  262
#define P_WRITE 774
#define RW_LD   1056   // 272 (read pad) + 784 (write pad)
#define W_OFF   272    // wp starts here inside rpwp row

typedef __attribute__((ext_vector_type(8))) short bf16x8;
typedef __attribute__((ext_vector_type(4))) float f32x4;

__device__ __forceinline__ float sigmoidf(float x) { return 1.f / (1.f + expf(-x)); }
__device__ __forceinline__ float softplusf(float x) { return (x > 20.f) ? x : log1pf(expf(x)); }

// ---------------- one-shot conversion / packing to bf16 (+ mem norms at grid tail) ----------------
#define N_WIH (3072*512)
#define N_WRW (RW_LD*1024)
#define N_WO  (512*1280)
#define N_X   (256*512)
#define N_MB  (512*256)
#define N_MT  (256*512)
#define N_BIA 3072
#define N_BRW RW_LD
#define N_TOT (N_WIH+N_WRW+N_WO+N_X+N_MB+N_MT+N_BIA+N_BRW)
#define NB_ELEM ((N_TOT + 255) / 256)

__global__ __launch_bounds__(256)
void convert_all(const float* __restrict__ W_ih, const float* __restrict__ b_ih,
                 const float* __restrict__ b_hh,
                 const float* __restrict__ W_read, const float* __restrict__ b_read,
                 const float* __restrict__ W_write, const float* __restrict__ b_write,
                 const float* __restrict__ W_out, const float* __restrict__ x,
                 const float* __restrict__ mem,
                 __hip_bfloat16* __restrict__ Wih_c, __hip_bfloat16* __restrict__ Wrw_p,
                 __hip_bfloat16* __restrict__ Wo_b, __hip_bfloat16* __restrict__ x_b,
                 __hip_bfloat16* __restrict__ mem_b, __hip_bfloat16* __restrict__ memT_b,
                 float* __restrict__ bias_c, float* __restrict__ bias_rw,
                 float* __restrict__ mem_norm)
{
    if (blockIdx.x >= NB_ELEM) {
        // mem row norm block
        __shared__ float red[4];
        int s = blockIdx.x - NB_ELEM;
        float v = mem[(size_t)s * WD + threadIdx.x];
        float vv = v * v;
        #pragma unroll
        for (int off = 32; off > 0; off >>= 1) vv += __shfl_down(vv, off, 64);
        int wid = threadIdx.x >> 6;
        if ((threadIdx.x & 63) == 0) red[wid] = vv;
        __syncthreads();
        if (threadIdx.x == 0)
            mem_norm[s] = fmaxf(sqrtf(red[0] + red[1] + red[2] + red[3]), 1e-8f);
        return;
    }
    long i = (long)blockIdx.x * 256 + threadIdx.x;
    if (i >= N_TOT) return;
    if (i < N_WIH) {   // compact i|g|o rows of W_ih, first 512 cols only
        int r = (int)(i >> 9), c = (int)(i & 511);
        int sr = r < 1024 ? r : r + 1024;    // skip f-gate rows
        Wih_c[i] = __float2bfloat16(W_ih[(size_t)sr * 768 + c]);
        return;
    }
    i -= N_WIH;
    if (i < N_WRW) {   // [Wr padded to 272 ; Ww padded to 784] x 1024
        int r = (int)(i >> 10), c = (int)(i & 1023);
        float v = 0.f;
        if (r < W_OFF) { if (r < P_READ) v = W_read[(size_t)r * 1024 + c]; }
        else { int wr = r - W_OFF; if (wr < P_WRITE) v = W_write[(size_t)wr * 1024 + c]; }
        Wrw_p[i] = __float2bfloat16(v);
        return;
    }
    i -= N_WRW;
    if (i < N_WO) { Wo_b[i] = __float2bfloat16(W_out[i]); return; }
    i -= N_WO;
    if (i < N_X)  { x_b[i] = __float2bfloat16(x[i]); return; }
    i -= N_X;
    if (i < N_MB) { mem_b[i] = __float2bfloat16(mem[i]); return; }
    i -= N_MB;
    if (i < N_MT) {
        int w = (int)(i >> 9), s = (int)(i & 511);
        memT_b[i] = __float2bfloat16(mem[(size_t)s * 256 + w]);
        return;
    }
    i -= N_MT;
    if (i < N_BIA) {
        int r = (int)i;
        int sr = r < 1024 ? r : r + 1024;
        bias_c[r] = b_ih[sr] + b_hh[sr];
        return;
    }
    i -= N_BIA;
    {
        int r = (int)i;
        float v = 0.f;
        if (r < W_OFF) { if (r < P_READ) v = b_read[r]; }
        else { int wr = r - W_OFF; if (wr < P_WRITE) v = b_write[wr]; }
        bias_rw[r] = v;
    }
}

// ---------------- gates GEMM + LSTM fused: h = lstm(x @ Wih_c^T + bias_c) -> hrv[:,0:1024] bf16 ----------------
// grid (64 j-tiles, 16 b-tiles), one wave per (b,j) 16x16 tile, 3 interleaved MFMA chains (i,g,o)
__global__ __launch_bounds__(64)
void gemm_gates(const __hip_bfloat16* __restrict__ x_b,
                const __hip_bfloat16* __restrict__ Wih_c,
                const float* __restrict__ bias_c,
                __hip_bfloat16* __restrict__ hrv)
{
    const int l = threadIdx.x;
    const int bn = blockIdx.x * 16;
    const int bm = blockIdx.y * 16;
    const int r = l & 15, q = l >> 4;
    const __hip_bfloat16* aptr = x_b + (size_t)(bm + r) * INW + q * 8;
    const __hip_bfloat16* bi = Wih_c + (size_t)(bn + r) * INW + q * 8;
    const __hip_bfloat16* bg = bi + (size_t)1024 * INW;
    const __hip_bfloat16* bo = bi + (size_t)2048 * INW;
    f32x4 ai = {0.f,0.f,0.f,0.f}, ag = ai, ao = ai;
    #pragma unroll
    for (int k = 0; k < INW; k += 32) {
        bf16x8 a = *reinterpret_cast<const bf16x8*>(aptr + k);
        ai = __builtin_amdgcn_mfma_f32_16x16x32_bf16(a, *reinterpret_cast<const bf16x8*>(bi + k), ai, 0, 0, 0);
        ag = __builtin_amdgcn_mfma_f32_16x16x32_bf16(a, *reinterpret_cast<const bf16x8*>(bg + k), ag, 0, 0, 0);
        ao = __builtin_amdgcn_mfma_f32_16x16x32_bf16(a, *reinterpret_cast<const bf16x8*>(bo + k), ao, 0, 0, 0);
    }
    const int j = bn + r;
    const float bii = bias_c[j], big = bias_c[1024 + j], bio = bias_c[2048 + j];
    #pragma unroll
    for (int jj = 0; jj < 4; ++jj) {
        int b = bm + q * 4 + jj;
        float gi = ai[jj] + bii, gg = ag[jj] + big, go = ao[jj] + bio;
        float c = sigmoidf(gi) * tanhf(gg);
        hrv[(size_t)b * 1280 + j] = __float2bfloat16(sigmoidf(go) * tanhf(c));
    }
}

// ---------------- generic MFMA GEMM: C[m,n] = sum_k A[m,k]*B[n,k] (+bias[n]) ----------------
// One wave per 16x16 tile, split-K dual accumulators. N, M multiples of 16, K multiple of 64.
// kcopy != null: dual-range keys harvest (cols 0..255 -> rows m; cols 272..527 -> rows 256+m)
__global__ __launch_bounds__(64)
void gemm_mfma(const __hip_bfloat16* __restrict__ A, int lda,
               const __hip_bfloat16* __restrict__ B, int ldb,
               const float* __restrict__ bias,
               float* __restrict__ C, int ldc, int K,
               __hip_bfloat16* __restrict__ kcopy)
{
    const int l = threadIdx.x;
    const int bn = blockIdx.x * 16;
    const int bm = blockIdx.y * 16;
    const int r = l & 15, q = l >> 4;
    const __hip_bfloat16* aptr = A + (size_t)(bm + r) * lda + q * 8;
    const __hip_bfloat16* bptr = B + (size_t)(bn + r) * ldb + q * 8;
    const int K2 = (K >> 6) << 5;
    f32x4 acc0 = {0.f,0.f,0.f,0.f}, acc1 = acc0;
    #pragma unroll 4
    for (int k = 0; k < K2; k += 32)
        acc0 = __builtin_amdgcn_mfma_f32_16x16x32_bf16(
            *reinterpret_cast<const bf16x8*>(aptr + k),
            *reinterpret_cast<const bf16x8*>(bptr + k), acc0, 0, 0, 0);
    #pragma unroll 4
    for (int k = K2; k < K; k += 32)
        acc1 = __builtin_amdgcn_mfma_f32_16x16x32_bf16(
            *reinterpret_cast<const bf16x8*>(aptr + k),
            *reinterpret_cast<const bf16x8*>(bptr + k), acc1, 0, 0, 0);
    const int col = bn + r;
    const float bv = bias ? bias[col] : 0.f;
    #pragma unroll
    for (int j = 0; j < 4; ++j) {
        int m = bm + q * 4 + j;
        float v = acc0[j] + acc1[j] + bv;
        C[(size_t)m * ldc + col] = v;
        if (kcopy) {
            if (col < WD)
                kcopy[(size_t)m * WD + col] = __float2bfloat16(v);
            else if (col >= W_OFF && col < W_OFF + WD)
                kcopy[(size_t)(256 + m) * WD + (col - W_OFF)] = __float2bfloat16(v);
        }
    }
}

// ---------------- fused addressing (read+write) + A12 pack + t3 ----------------
// one block (512 threads) per batch
__device__ __forceinline__ void redpair_sum(float& a, float& b, volatile float* redA, volatile float* redB) {
    #pragma unroll
    for (int off = 32; off > 0; off >>= 1) { a += __shfl_down(a, off, 64); b += __shfl_down(b, off, 64); }
    int wid = threadIdx.x >> 6;
    __syncthreads();
    if ((threadIdx.x & 63) == 0) { redA[wid] = a; redB[wid] = b; }
    __syncthreads();
    a = redA[0]+redA[1]+redA[2]+redA[3]+redA[4]+redA[5]+redA[6]+redA[7];
    b = redB[0]+redB[1]+redB[2]+redB[3]+redB[4]+redB[5]+redB[6]+redB[7];
}
__device__ __forceinline__ void redpair_max(float& a, float& b, volatile float* redA, volatile float* redB) {
    #pragma unroll
    for (int off = 32; off > 0; off >>= 1) { a = fmaxf(a, __shfl_down(a, off, 64)); b = fmaxf(b, __shfl_down(b, off, 64)); }
    int wid = threadIdx.x >> 6;
    __syncthreads();
    if ((threadIdx.x & 63) == 0) { redA[wid] = a; redB[wid] = b; }
    __syncthreads();
    a = fmaxf(fmaxf(fmaxf(redA[0],redA[1]),fmaxf(redA[2],redA[3])),fmaxf(fmaxf(redA[4],redA[5]),fmaxf(redA[6],redA[7])));
    b = fmaxf(fmaxf(fmaxf(redB[0],redB[1]),fmaxf(redB[2],redB[3])),fmaxf(fmaxf(redB[4],redB[5]),fmaxf(redB[6],redB[7])));
}

__global__ __launch_bounds__(512)
void address_fused(const float* __restrict__ rpwp, const float* __restrict__ num,
                   const float* __restrict__ mem_norm,
                   __hip_bfloat16* __restrict__ A12, float* __restrict__ t3)
{
    const int b = blockIdx.x;
    const int t = threadIdx.x;            // 0..511 = memory slot
    const float* pr = rpwp + (size_t)b * RW_LD;
    const float* pw = pr + W_OFF;

    __shared__ float redA[8], redB[8];
    __shared__ float bufr[SS], bufw[SS];

    // header params (broadcast reads)
    float beta_r  = softplusf(pr[WD]);
    float gate_r  = sigmoidf(pr[WD + 1]);
    float r0 = pr[WD+2], r1 = pr[WD+3], r2 = pr[WD+4];
    float rmx = fmaxf(r0, fmaxf(r1, r2));
    float re0 = expf(r0-rmx), re1 = expf(r1-rmx), re2 = expf(r2-rmx);
    float rinv = 1.f / (re0+re1+re2);
    float shr0 = re0*rinv, shr1 = re1*rinv, shr2 = re2*rinv;
    float gamma_r = 1.f + softplusf(pr[WD + 5]);

    float beta_w  = softplusf(pw[WD]);
    float gate_w  = sigmoidf(pw[WD + 1]);
    float w0 = pw[WD+2], w1 = pw[WD+3], w2 = pw[WD+4];
    float wmx = fmaxf(w0, fmaxf(w1, w2));
    float we0 = expf(w0-wmx), we1 = expf(w1-wmx), we2 = expf(w2-wmx);
    float winv = 1.f / (we0+we1+we2);
    float shw0 = we0*winv, shw1 = we1*winv, shw2 = we2*winv;
    float gamma_w = 1.f + softplusf(pw[WD + 5]);

    // key norms: threads 0..255 (waves 0..3) read key_r, 256..511 (waves 4..7) key_w
    {
        float kv = (t < WD) ? pr[t] : pw[t - WD];
        float vv = kv * kv;
        #pragma unroll
        for (int off = 32; off > 0; off >>= 1) vv += __shfl_down(vv, off, 64);
        int wid = t >> 6;
        if ((t & 63) == 0) redA[wid] = vv;
        __syncthreads();
    }
    float knr = fmaxf(sqrtf(redA[0]+redA[1]+redA[2]+redA[3]), 1e-8f);
    float knw = fmaxf(sqrtf(redA[4]+redA[5]+redA[6]+redA[7]), 1e-8f);
    __syncthreads();

    // cosine sims
    float mni = 1.f / mem_norm[t];
    float sim_r = num[(size_t)b * SS + t]         * mni / knr * beta_r;
    float sim_w = num[(size_t)(256 + b) * SS + t] * mni / knw * beta_w;

    // softmax over 512 slots (both at once)
    float mr = sim_r, mw = sim_w;
    redpair_max(mr, mw, redA, redB);
    float exr = expf(sim_r - mr), exw = expf(sim_w - mw);
    float sr = exr, sw = exw;
    redpair_sum(sr, sw, redA, redB);
    float cwr = exr / sr, cww = exw / sw;

    // gate with prev_w = one-hot(0)
    float onehot = (t == 0) ? 1.f : 0.f;
    float gwr = gate_r * cwr + (1.f - gate_r) * onehot;
    float gww = gate_w * cww + (1.f - gate_w) * onehot;
    __syncthreads();
    bufr[t] = gwr; bufw[t] = gww;
    __syncthreads();

    // cyclic shift
    int tm = (t + SS - 1) & (SS - 1), tp = (t + 1) & (SS - 1);
    float swr = shr0 * bufr[tm] + shr1 * gwr + shr2 * bufr[tp];
    float sww = shw0 * bufw[tm] + shw1 * gww + shw2 * bufw[tp];

    // sharpen + normalize
    float spr = powf(swr, gamma_r), spw = powf(sww, gamma_w);
    float ssr = spr, ssw = spw;
    redpair_sum(ssr, ssw, redA, redB);
    float rfin = spr / (ssr + 1e-6f);
    float wfin = spw / (ssw + 1e-6f);

    // pack A12 + t3
    float prod = rfin * wfin;
    A12[(size_t)b * SS + t] = __float2bfloat16(rfin);
    A12[(size_t)(256 + b) * SS + t] = __float2bfloat16(prod);
    float tp3 = prod, dummy = 0.f;
    redpair_sum(tp3, dummy, redA, redB);
    if (t == 0) t3[b] = tp3;
}

// ---------------- t12 GEMM + rv epilogue: rv = t1 - erase*t2 + add*t3 -> hrv[:,1024:1280] bf16 ----------------
// grid (16 w-tiles, 16 b-tiles); two chains per wave (t1 from read_w rows, t2 from rw_prod rows)
__global__ __launch_bounds__(64)
void gemm_t12rv(const __hip_bfloat16* __restrict__ A12,
                const __hip_bfloat16* __restrict__ memT_b,
                const float* __restrict__ rpwp, const float* __restrict__ t3,
                __hip_bfloat16* __restrict__ hrv)
{
    const int l = threadIdx.x;
    const int bn = blockIdx.x * 16;   // w
    const int bm = blockIdx.y * 16;   // b
    const int r = l & 15, q = l >> 4;
    const __hip_bfloat16* a1 = A12 + (size_t)(bm + r) * SS + q * 8;
    const __hip_bfloat16* a2 = a1 + (size_t)256 * SS;
    const __hip_bfloat16* bp = memT_b + (size_t)(bn + r) * SS + q * 8;
    f32x4 acc1 = {0.f,0.f,0.f,0.f}, acc2 = acc1;
    #pragma unroll
    for (int k = 0; k < SS; k += 32) {
        bf16x8 bb = *reinterpret_cast<const bf16x8*>(bp + k);
        acc1 = __builtin_amdgcn_mfma_f32_16x16x32_bf16(*reinterpret_cast<const bf16x8*>(a1 + k), bb, acc1, 0, 0, 0);
        acc2 = __builtin_amdgcn_mfma_f32_16x16x32_bf16(*reinterpret_cast<const bf16x8*>(a2 + k), bb, acc2, 0, 0, 0);
    }
    const int w = bn + r;
    #pragma unroll
    for (int j = 0; j < 4; ++j) {
        int b = bm + q * 4 + j;
        const float* row = rpwp + (size_t)b * RW_LD;
        float e = sigmoidf(row[W_OFF + P_READ + w]);
        float a = tanhf(row[W_OFF + P_READ + WD + w]);
        float rv = acc1[j] - e * acc2[j] + a * t3[b];
        hrv[(size_t)b * 1280 + 1024 + w] = __float2bfloat16(rv);
    }
}

// ---------------- host launcher ----------------
extern "C" void kernel_launch(void* const* d_in, const int* in_sizes, int n_in,
                              void* d_out, int out_size, void* d_ws, size_t ws_size,
                              hipStream_t stream)
{
    const float* x       = (const float*)d_in[0];
    const float* W_ih    = (const float*)d_in[1];
    const float* b_ih    = (const float*)d_in[2];
    const float* b_hh    = (const float*)d_in[4];
    const float* W_read  = (const float*)d_in[5];
    const float* b_read  = (const float*)d_in[6];
    const float* W_write = (const float*)d_in[7];
    const float* b_write = (const float*)d_in[8];
    const float* W_out   = (const float*)d_in[9];
    const float* b_out   = (const float*)d_in[10];
    const float* mem     = (const float*)d_in[11];

    float* ws = (float*)d_ws;
    float* rpwp     = ws;                 // 256*1056 = 270336
    float* num      = ws + 270336;        // 512*512  = 262144
    float* bias_c   = ws + 532480;        // 3072
    float* bias_rw  = ws + 535552;        // 1056
    float* mem_norm = ws + 536608;        // 512
    float* t3       = ws + 537120;        // 256
    __hip_bfloat16* bfb = (__hip_bfloat16*)(ws + 537376);
    __hip_bfloat16* x_b    = bfb;                 // 131072
    __hip_bfloat16* Wih_c  = bfb + 131072;        // 1572864
    __hip_bfloat16* Wrw_p  = bfb + 1703936;       // 1081344
    __hip_bfloat16* Wo_b   = bfb + 2785280;       // 655360
    __hip_bfloat16* mem_b  = bfb + 3440640;       // 131072
    __hip_bfloat16* memT_b = bfb + 3571712;       // 131072
    __hip_bfloat16* A12    = bfb + 3702784;       // 262144
    __hip_bfloat16* hrv    = bfb + 3964928;       // 327680
    __hip_bfloat16* keys   = bfb + 4292608;       // 131072
    float* out = (float*)d_out;

    // 1. convert/pack + mem norms
    convert_all<<<NB_ELEM + SS, 256, 0, stream>>>(
        W_ih, b_ih, b_hh, W_read, b_read, W_write, b_write, W_out, x, mem,
        Wih_c, Wrw_p, Wo_b, x_b, mem_b, memT_b, bias_c, bias_rw, mem_norm);
    // 2. gates GEMM + LSTM -> h in hrv[:,0:1024]
    gemm_gates<<<dim3(64, 16), 64, 0, stream>>>(x_b, Wih_c, bias_c, hrv);
    // 3. rpwp = h @ [Wr;Ww]^T + bias ; harvest keys (rows 0..255 read, 256..511 write)
    gemm_mfma<<<dim3(66, 16), 64, 0, stream>>>(hrv, 1280, Wrw_p, HH, bias_rw,
                                               rpwp, RW_LD, HH, keys);
    // 4. num = keys @ mem^T  [512 x 512]
    gemm_mfma<<<dim3(32, 32), 64, 0, stream>>>(keys, WD, mem_b, WD, nullptr,
                                               num, SS, WD, nullptr);
    // 5. addressing (read & write) + A12 + t3
    address_fused<<<BB, 512, 0, stream>>>(rpwp, num, mem_norm, A12, t3);
    // 6. t12 GEMM + rv -> hrv[:,1024:1280]
    gemm_t12rv<<<dim3(16, 16), 64, 0, stream>>>(A12, memT_b, rpwp, t3, hrv);
    // 7. out = hrv @ W_out^T + b_out
    gemm_mfma<<<dim3(32, 16), 64, 0, stream>>>(hrv, 1280, Wo_b, 1280, b_out,
                                               out, OUTW, 1280, nullptr);
}